// Round 12
// baseline (180.725 us; speedup 1.0000x reference)
//
#include <hip/hip_runtime.h>
#include <hip/hip_fp16.h>
#include <math.h>

#ifndef M_PI
#define M_PI 3.14159265358979323846
#endif

#define SS   129
#define LL   224
#define LL2  (LL*LL)
#define LL3  (LL*LL*LL)
#define SS2  (SS*SS)
#define SS3  (SS*SS*SS)
#define CABS 0.2f
#define PAD  48

#define BLO 45.5f
#define BHI 178.5f

#define NT1  28                  // 8-tile grid per axis (Run/Ssum granularity)
#define NTZ16 14                 // 16-deep rot super-tiles along z
#define ROTG  (2 * NTZ16 * 784)  // 21952 blocks
#define NT3  17
#define NBZ16 9                  // 16-deep back super-tiles (ceil(129/16))
#define BACKG (2 * NBZ16 * 289)  // 5202 blocks
#define NTZ  28
#define NSEG 4
#define SEGZ 33

// k_rot staging box: [y:16][z:18][x:21]  (x stride 1, z stride 21, y stride 378)
#define RBX 21
#define RBY 16
#define RBZ 18
#define RBN (RBX*RBY*RBZ)        // 6048 words
#define RSXZ (RBX*RBZ)           // 378 staging threads

// k_back staging box: [y:16][z:19][x:21] (y stride 399, z stride 21)
#define BBX 21
#define BBY 16
#define BBZ 19
#define BBN (BBX*BBY*BBZ)        // 6384 words
#define BSXZ (BBX*BBZ)           // 399 staging threads

struct Mat3 { float m[9]; };
struct F3   { float x, y, z; };

// 8-tile center (Run granularity)
__device__ __forceinline__ F3 tile_center(const Mat3& M, int ox, int oy, int oz) {
    float cbx = fmaf((float)ox + 3.5f, 2.0f / 223.0f, -1.0f);
    float cby = fmaf((float)oy + 3.5f, 2.0f / 223.0f, -1.0f);
    float cbz = fmaf((float)oz + 3.5f, 2.0f / 223.0f, -1.0f);
    F3 qc;
    qc.x = fmaf(fmaf(M.m[0], cbx, fmaf(M.m[1], cby, M.m[2] * cbz)), 111.5f, 111.5f);
    qc.y = fmaf(fmaf(M.m[3], cbx, fmaf(M.m[4], cby, M.m[5] * cbz)), 111.5f, 111.5f);
    qc.z = fmaf(fmaf(M.m[6], cbx, fmaf(M.m[7], cby, M.m[8] * cbz)), 111.5f, 111.5f);
    return qc;
}

// 16-deep super-tile center
__device__ __forceinline__ F3 tile_center16(const Mat3& M, int ox, int oy, int oz) {
    float cbx = fmaf((float)ox + 3.5f, 2.0f / 223.0f, -1.0f);
    float cby = fmaf((float)oy + 3.5f, 2.0f / 223.0f, -1.0f);
    float cbz = fmaf((float)oz + 7.5f, 2.0f / 223.0f, -1.0f);
    F3 qc;
    qc.x = fmaf(fmaf(M.m[0], cbx, fmaf(M.m[1], cby, M.m[2] * cbz)), 111.5f, 111.5f);
    qc.y = fmaf(fmaf(M.m[3], cbx, fmaf(M.m[4], cby, M.m[5] * cbz)), 111.5f, 111.5f);
    qc.z = fmaf(fmaf(M.m[6], cbx, fmaf(M.m[7], cby, M.m[8] * cbz)), 111.5f, 111.5f);
    return qc;
}

__device__ __forceinline__ bool tile_accept(F3 qc, F3 H) {
    return !(qc.x + H.x < BLO || qc.x - H.x > BHI ||
             qc.y + H.y < BLO || qc.y - H.y > BHI ||
             qc.z + H.z < BLO || qc.z - H.z > BHI);
}

__device__ __forceinline__ void qmap(const Mat3& M, int x, int y, int z,
                                     float& qx, float& qy, float& qz) {
    float bx = fmaf((float)x, 2.0f / 223.0f, -1.0f);
    float by = fmaf((float)y, 2.0f / 223.0f, -1.0f);
    float bz = fmaf((float)z, 2.0f / 223.0f, -1.0f);
    qx = fmaf(fmaf(M.m[0], bx, fmaf(M.m[1], by, M.m[2] * bz)), 111.5f, 111.5f);
    qy = fmaf(fmaf(M.m[3], bx, fmaf(M.m[4], by, M.m[5] * bz)), 111.5f, 111.5f);
    qz = fmaf(fmaf(M.m[6], bx, fmaf(M.m[7], by, M.m[8] * bz)), 111.5f, 111.5f);
}

__device__ __forceinline__ float fetch_d(const float* __restrict__ d, int z, int y, int x) {
    unsigned zz = (unsigned)(z - PAD), yy = (unsigned)(y - PAD), xx = (unsigned)(x - PAD);
    return (zz < (unsigned)SS && yy < (unsigned)SS && xx < (unsigned)SS)
        ? d[((int)zz * SS + (int)yy) * SS + (int)xx] : 0.0f;
}

__device__ __forceinline__ float fetch_T(const float* __restrict__ T, int z, int y, int x) {
    unsigned zz = (unsigned)z, yy = (unsigned)y, xx = (unsigned)x;
    return (zz < (unsigned)LL && yy < (unsigned)LL && xx < (unsigned)LL)
        ? T[((int)zz * LL + (int)yy) * LL + (int)xx] : 0.0f;
}

__device__ __forceinline__ float tri_T(const float* __restrict__ T, float qz, float qy, float qx) {
    int x0 = (int)floorf(qx), y0 = (int)floorf(qy), z0 = (int)floorf(qz);
    float wx = qx - (float)x0, wy = qy - (float)y0, wz = qz - (float)z0;
    float c000 = fetch_T(T, z0, y0, x0),     c001 = fetch_T(T, z0, y0, x0 + 1);
    float c010 = fetch_T(T, z0, y0 + 1, x0), c011 = fetch_T(T, z0, y0 + 1, x0 + 1);
    float c100 = fetch_T(T, z0 + 1, y0, x0),     c101 = fetch_T(T, z0 + 1, y0, x0 + 1);
    float c110 = fetch_T(T, z0 + 1, y0 + 1, x0), c111 = fetch_T(T, z0 + 1, y0 + 1, x0 + 1);
    float a00 = c000 + wx * (c001 - c000), a01 = c010 + wx * (c011 - c010);
    float a10 = c100 + wx * (c101 - c100), a11 = c110 + wx * (c111 - c110);
    float b0 = a00 + wy * (a01 - a00), b1 = a10 + wy * (a11 - a10);
    return b0 + wz * (b1 - b0);
}

__device__ __forceinline__ float tri_d_g(const float* __restrict__ d, float qz, float qy, float qx) {
    int x0 = (int)floorf(qx), y0 = (int)floorf(qy), z0 = (int)floorf(qz);
    float wx = qx - (float)x0, wy = qy - (float)y0, wz = qz - (float)z0;
    float c000 = fetch_d(d, z0, y0, x0),     c001 = fetch_d(d, z0, y0, x0 + 1);
    float c010 = fetch_d(d, z0, y0 + 1, x0), c011 = fetch_d(d, z0, y0 + 1, x0 + 1);
    float c100 = fetch_d(d, z0 + 1, y0, x0),     c101 = fetch_d(d, z0 + 1, y0, x0 + 1);
    float c110 = fetch_d(d, z0 + 1, y0 + 1, x0), c111 = fetch_d(d, z0 + 1, y0 + 1, x0 + 1);
    float a00 = c000 + wx * (c001 - c000), a01 = c010 + wx * (c011 - c010);
    float a10 = c100 + wx * (c101 - c100), a11 = c110 + wx * (c111 - c110);
    float b0 = a00 + wy * (a01 - a00), b1 = a10 + wy * (a11 - a10);
    return b0 + wz * (b1 - b0);
}

// trilinear from k_rot's [y:16][z:18][x:21] box
__device__ __forceinline__ float tri_rot(const float* __restrict__ S,
                                         float qx, float qy, float qz,
                                         int lox, int loy, int loz) {
    int x0 = (int)floorf(qx), y0 = (int)floorf(qy), z0 = (int)floorf(qz);
    float wx = qx - (float)x0, wy = qy - (float)y0, wz = qz - (float)z0;
    int i = (y0 - loy) * 378 + (z0 - loz) * 21 + (x0 - lox);
    float c000 = S[i],        c001 = S[i + 1];
    float cz0  = S[i + 21],   cz1  = S[i + 22];
    float cy0  = S[i + 378],  cy1  = S[i + 379];
    float cw0  = S[i + 399],  cw1  = S[i + 400];
    float a00 = c000 + wx * (c001 - c000);
    float a01 = cy0  + wx * (cy1  - cy0);
    float a10 = cz0  + wx * (cz1  - cz0);
    float a11 = cw0  + wx * (cw1  - cw0);
    float b0  = a00 + wy * (a01 - a00);
    float b1  = a10 + wy * (a11 - a10);
    return b0 + wz * (b1 - b0);
}

// trilinear from k_back's [y:16][z:19][x:21] box
__device__ __forceinline__ float tri_back(const float* __restrict__ S,
                                          float qx, float qy, float qz,
                                          int lox, int loy, int loz) {
    int x0 = (int)floorf(qx), y0 = (int)floorf(qy), z0 = (int)floorf(qz);
    float wx = qx - (float)x0, wy = qy - (float)y0, wz = qz - (float)z0;
    int i = (y0 - loy) * 399 + (z0 - loz) * 21 + (x0 - lox);
    float c000 = S[i],        c001 = S[i + 1];
    float cz0  = S[i + 21],   cz1  = S[i + 22];
    float cy0  = S[i + 399],  cy1  = S[i + 400];
    float cw0  = S[i + 420],  cw1  = S[i + 421];
    float a00 = c000 + wx * (c001 - c000);
    float a01 = cy0  + wx * (cy1  - cy0);
    float a10 = cz0  + wx * (cz1  - cz0);
    float a11 = cw0  + wx * (cw1  - cw0);
    float b0  = a00 + wy * (a01 - a00);
    float b1  = a10 + wy * (a11 - a10);
    return b0 + wz * (b1 - b0);
}

// k_pre: blocks [0,261): view-ray segment sums + zero accumulators;
//        blocks [261,268): Run table build (8-tile granularity, accept8)
__global__ __launch_bounds__(256) void k_pre(const float* __restrict__ d,
        float* __restrict__ Dseg, float* __restrict__ A,
        unsigned short* __restrict__ Run, Mat3 M0, Mat3 M1, F3 H0, F3 H1) {
    int b = blockIdx.x;
    if (b < 261) {
        int t = b * 256 + threadIdx.x;
        if (t < 2 * SS2) A[t] = 0.0f;
        if (t >= NSEG * SS2) return;
        int seg = t / SS2, col = t - seg * SS2;
        int zs = seg * SEGZ, ze = min(SS, zs + SEGZ);
        float run = 0.0f;
        for (int z = zs; z < ze; ++z) run += d[z * SS2 + col];
        Dseg[t] = run;
    } else {
        int id = (b - 261) * 256 + threadIdx.x;
        if (id >= 2 * 784) return;
        int l = id / 784, r = id - l * 784;
        int ty = r / 28, tx = r - ty * 28;
        const Mat3 M = l ? M1 : M0;
        const F3  H  = l ? H1 : H0;
        int t0 = -1, t1 = -1;
        for (int tz = 0; tz < NT1; ++tz) {
            F3 qc = tile_center(M, tx * 8, ty * 8, tz * 8);
            if (tile_accept(qc, H)) { if (t0 < 0) t0 = tz; t1 = tz; }
        }
        Run[id] = (t0 < 0) ? 0xFFFFu : (unsigned short)(t0 | (t1 << 8));
    }
}

// K1: 8x8x16 super-tile per block; processed iff the column's accepted-8-tile
// run [t0,t1] overlaps the supertile's subtiles (write-set still covers every
// cell k_back can read — those lie in accept8 tiles, all inside [t0,t1]).
__global__ __launch_bounds__(512) void k_rot(const float* __restrict__ d,
        __half* __restrict__ T0, __half* __restrict__ T1,
        float* __restrict__ S0, float* __restrict__ S1,
        const unsigned short* __restrict__ Run,
        Mat3 M0, Mat3 M1, F3 H0, F3 H1) {
    int b = blockIdx.x;
    int light = b / (NTZ16 * 784);
    int r = b - light * (NTZ16 * 784);
    int tz16 = r / 784;
    int r2 = r - tz16 * 784;
    int tty = r2 / 28, ttx = r2 - tty * 28;

    unsigned short rt = Run[light * 784 + tty * 28 + ttx];
    if (rt == 0xFFFFu) return;
    int t0 = rt & 0xFF, t1 = rt >> 8;
    if (2 * tz16 + 1 < t0 || 2 * tz16 > t1) return;

    const Mat3 M = light ? M1 : M0;
    const F3  H  = light ? H1 : H0;           // H16
    __half* __restrict__ T   = light ? T1 : T0;
    float* __restrict__ Ssum = light ? S1 : S0;

    int ox = ttx * 8, oy = tty * 8, oz = tz16 * 16;
    F3 qc = tile_center16(M, ox, oy, oz);

    int lox = (int)floorf(qc.x - H.x);
    int loy = (int)floorf(qc.y - H.y);
    int loz = (int)floorf(qc.z - H.z);

    __shared__ float S[RBN];
    __shared__ float Sc[1024];
    int tid = threadIdx.x;

    if (tid < RSXZ) {
        int ix = tid % RBX, iz = tid / RBX;
        bool interior = (lox >= PAD) & (lox <= PAD + SS - RBX) &
                        (loy >= PAD) & (loy <= PAD + SS - RBY) &
                        (loz >= PAD) & (loz <= PAD + SS - RBZ);
        if (interior) {
            const float* g = d + ((size_t)(loz + iz - PAD) * SS + (loy - PAD)) * SS
                               + (lox + ix - PAD);
            #pragma unroll
            for (int j = 0; j < RBY; ++j)
                S[tid + j * RSXZ] = g[j * SS];
        } else {
            #pragma unroll
            for (int j = 0; j < RBY; ++j)
                S[tid + j * RSXZ] = fetch_d(d, loz + iz, loy + j, lox + ix);
        }
    }
    __syncthreads();

    int lx = tid & 7, ly = (tid >> 3) & 7, lz = tid >> 6;
    int col = tid & 63;
    float fx = (float)lx - 3.5f, fy = (float)ly - 3.5f, fz = (float)lz - 7.5f;
    float qx = qc.x + fmaf(M.m[0], fx, fmaf(M.m[1], fy, M.m[2] * fz));
    float qy = qc.y + fmaf(M.m[3], fx, fmaf(M.m[4], fy, M.m[5] * fz));
    float qz = qc.z + fmaf(M.m[6], fx, fmaf(M.m[7], fy, M.m[8] * fz));
    float v0 = tri_rot(S, qx, qy, qz, lox, loy, loz);
    float qx2 = qx + 8.0f * M.m[2];
    float qy2 = qy + 8.0f * M.m[5];
    float qz2 = qz + 8.0f * M.m[8];
    float v1 = tri_rot(S, qx2, qy2, qz2, lox, loy, loz);

    Sc[lz * 64 + col] = v0;
    Sc[(lz + 8) * 64 + col] = v1;
    __syncthreads();
    if (tid < 64) {
        int so = (oy + (tid >> 3)) * LL + (ox + (tid & 7));
        float s = 0.0f;
        #pragma unroll
        for (int k = 15; k >= 8; --k) { s += Sc[k * 64 + tid]; Sc[k * 64 + tid] = s; }
        Ssum[(2 * tz16 + 1) * LL2 + so] = s;
        float s2 = 0.0f;
        #pragma unroll
        for (int k = 7; k >= 0; --k) { s2 += Sc[k * 64 + tid]; Sc[k * 64 + tid] = s2; }
        Ssum[(2 * tz16) * LL2 + so] = s2;
    }
    __syncthreads();
    int to = (oy + ly) * LL + (ox + lx);
    T[(size_t)(oz + lz) * LL2 + to]     = __float2half(Sc[lz * 64 + col]);
    T[(size_t)(oz + 8 + lz) * LL2 + to] = __float2half(Sc[(lz + 8) * 64 + col]);
}

// k_sufw: blocks [0,392): per-column exclusive suffix-above of tile totals;
//         blocks [392,653): W write
__global__ __launch_bounds__(256) void k_sufw(float* __restrict__ S0,
        float* __restrict__ S1, const unsigned short* __restrict__ Run,
        const float* __restrict__ d, const float* __restrict__ Dseg,
        float* __restrict__ W) {
    int b = blockIdx.x;
    if (b < 392) {
        int l = b / 196;
        int col = (b - l * 196) * 256 + threadIdx.x;   // < LL2 exactly
        float* __restrict__ Ssum = l ? S1 : S0;
        int x = col % LL, y = col / LL;
        unsigned short r = Run[l * 784 + (y >> 3) * 28 + (x >> 3)];
        if (r == 0xFFFFu) return;
        int t0 = r & 0xFF, t1 = r >> 8;
        float vbuf[NTZ];
        #pragma unroll
        for (int t = 0; t < NTZ; ++t)
            vbuf[t] = (t >= t0 && t <= t1) ? Ssum[t * LL2 + col] : 0.0f;
        float run = 0.0f;
        #pragma unroll
        for (int t = NTZ - 1; t >= 0; --t) {
            if (t >= t0 && t <= t1) Ssum[t * LL2 + col] = run;
            run += vbuf[t];
        }
    } else {
        int t = (b - 392) * 256 + threadIdx.x;
        if (t >= NSEG * SS2) return;
        int seg = t / SS2, col = t - seg * SS2;
        int zs = seg * SEGZ, ze = min(SS, zs + SEGZ);
        float run = 0.0f;
        for (int s2 = seg + 1; s2 < NSEG; ++s2) run += Dseg[s2 * SS2 + col];
        for (int z = ze - 1; z >= zs; --z) {
            float dv = d[z * SS2 + col];
            run += dv;
            W[z * SS2 + col] = dv * __expf(-CABS * run);
        }
    }
}

// K3: 8x8x16 super-tile; stage exp(-c*(T16+seed)) into LDS, back-rotate,
// multiply by W, reduce 16 z-lanes per column, one atomic per column.
template<bool BINT>
__global__ __launch_bounds__(512) void k_back(const __half* __restrict__ T0,
        const __half* __restrict__ T1, const float* __restrict__ S0,
        const float* __restrict__ S1, const float* __restrict__ W,
        float* __restrict__ A0, float* __restrict__ A1,
        Mat3 M0, Mat3 M1, F3 H0, F3 H1) {
    int b = blockIdx.x;
    int light = b / (NBZ16 * 289); b -= light * (NBZ16 * 289);
    int tz16 = b / 289;
    int r2 = b - tz16 * 289;
    int tty = r2 / 17, ttx = r2 - tty * 17;

    const Mat3 M = light ? M1 : M0;
    const F3  H  = light ? H1 : H0;           // H16 (back)
    const __half* __restrict__ T   = light ? T1 : T0;
    const float* __restrict__ Ssum = light ? S1 : S0;
    float* __restrict__ A = light ? A1 : A0;

    int ox = ttx * 8, oy = tty * 8, oz = tz16 * 16;
    F3 qc = tile_center16(M, ox + PAD, oy + PAD, oz + PAD);
    int lox = (int)floorf(qc.x - H.x);
    int loy = (int)floorf(qc.y - H.y);
    int loz = (int)floorf(qc.z - H.z);

    __shared__ float S[BBN];
    __shared__ float Sc[1024];
    int tid = threadIdx.x;

    if (tid < BSXZ) {
        int ix = tid % BBX, iz = tid / BBX;
        if (BINT) {
            const __half* tb = T + ((size_t)(loz + iz) * LL + loy) * LL + (lox + ix);
            const float* sb = Ssum + (size_t)((loz + iz) >> 3) * LL2 + loy * LL + (lox + ix);
            #pragma unroll
            for (int j = 0; j < BBY; ++j)
                S[tid + j * BSXZ] = __expf(-CABS * (__half2float(tb[j * LL]) + sb[j * LL]));
        } else {
            #pragma unroll
            for (int j = 0; j < BBY; ++j) {
                int gz = loz + iz, gy = loy + j, gx = lox + ix;
                bool inb = ((unsigned)gz < (unsigned)LL) & ((unsigned)gy < (unsigned)LL)
                         & ((unsigned)gx < (unsigned)LL);
                float e = 0.0f;
                if (inb)
                    e = __expf(-CABS * (__half2float(T[((size_t)gz * LL + gy) * LL + gx])
                                      + Ssum[(size_t)(gz >> 3) * LL2 + gy * LL + gx]));
                S[tid + j * BSXZ] = e;
            }
        }
    }
    __syncthreads();

    int lx = tid & 7, ly = (tid >> 3) & 7, lz = tid >> 6;
    int col = tid & 63;
    int x = ox + lx, y = oy + ly;
    float v0 = 0.0f, v1 = 0.0f;
    if (x < SS && y < SS) {
        float fx = (float)lx - 3.5f, fy = (float)ly - 3.5f, fz = (float)lz - 7.5f;
        float qx = qc.x + fmaf(M.m[0], fx, fmaf(M.m[1], fy, M.m[2] * fz));
        float qy = qc.y + fmaf(M.m[3], fx, fmaf(M.m[4], fy, M.m[5] * fz));
        float qz = qc.z + fmaf(M.m[6], fx, fmaf(M.m[7], fy, M.m[8] * fz));
        int z0 = oz + lz, z1 = oz + 8 + lz;
        if (z0 < SS)
            v0 = tri_back(S, qx, qy, qz, lox, loy, loz) * W[(z0 * SS + y) * SS + x];
        if (z1 < SS) {
            float qx2 = qx + 8.0f * M.m[2];
            float qy2 = qy + 8.0f * M.m[5];
            float qz2 = qz + 8.0f * M.m[8];
            v1 = tri_back(S, qx2, qy2, qz2, lox, loy, loz) * W[(z1 * SS + y) * SS + x];
        }
    }
    Sc[lz * 64 + col] = v0;
    Sc[(lz + 8) * 64 + col] = v1;
    __syncthreads();
    if (tid < 64) {
        float s = 0.0f;
        #pragma unroll
        for (int k = 0; k < 16; ++k) s += Sc[k * 64 + tid];
        int xx = ox + (tid & 7), yy = oy + (tid >> 3);
        if (xx < SS && yy < SS) atomicAdd(&A[yy * SS + xx], s);
    }
}

__global__ __launch_bounds__(256) void k_combine(const float* __restrict__ A0,
        const float* __restrict__ A1, float* __restrict__ out, F3 c0, F3 c1) {
    int i = blockIdx.x * 256 + threadIdx.x;
    if (i >= 3 * SS2) return;
    int ch = i / SS2, col = i - ch * SS2;
    float r0 = (ch == 0) ? c0.x : ((ch == 1) ? c0.y : c0.z);
    float r1 = (ch == 0) ? c1.x : ((ch == 1) ? c1.y : c1.z);
    float o = CABS * (A0[col] * r0 + A1[col] * r1);
    out[i] = fminf(fmaxf(o, 0.0f), 1.0f);
}

// ---- minimal-workspace fallback ----
__global__ __launch_bounds__(256) void k_rot_full(const float* __restrict__ d,
                                                  float* __restrict__ T, Mat3 R) {
    int i = blockIdx.x * 256 + threadIdx.x;
    if (i >= LL3) return;
    int x = i % LL; int r = i / LL; int y = r % LL; int z = r / LL;
    float qx, qy, qz; qmap(R, x, y, z, qx, qy, qz);
    T[i] = tri_d_g(d, qz, qy, qx);
}

__global__ __launch_bounds__(256) void k_scan_full(float* __restrict__ T) {
    int col = blockIdx.x * 256 + threadIdx.x;
    if (col >= LL2) return;
    float run = 0.0f;
    for (int z = LL - 1; z >= 0; --z) {
        int idx = z * LL2 + col;
        run += T[idx];
        T[idx] = __expf(-CABS * run);
    }
}

__global__ __launch_bounds__(64) void k_fused_back(const float* __restrict__ T,
        const float* __restrict__ d, float* __restrict__ LA, Mat3 RT,
        float cr, float cg, float cb, int first) {
    int col = blockIdx.x * 64 + threadIdx.x;
    if (col >= SS2) return;
    int y = col / SS, x = col % SS;
    float run = 0.0f, acc = 0.0f;
    for (int z = SS - 1; z >= 0; --z) {
        float qx, qy, qz; qmap(RT, x + PAD, y + PAD, z + PAD, qx, qy, qz);
        float u = tri_T(T, qz, qy, qx);
        float dv = d[z * SS2 + col];
        run += dv;
        acc = fmaf(dv * __expf(-CABS * run), u, acc);
    }
    if (first) {
        LA[0 * SS2 + col] = acc * cr;
        LA[1 * SS2 + col] = acc * cg;
        LA[2 * SS2 + col] = acc * cb;
    } else {
        LA[0 * SS2 + col] += acc * cr;
        LA[1 * SS2 + col] += acc * cg;
        LA[2 * SS2 + col] += acc * cb;
    }
}

__global__ __launch_bounds__(256) void k_clip(const float* __restrict__ LA,
                                              float* __restrict__ out) {
    int i = blockIdx.x * 256 + threadIdx.x;
    if (i < 3 * SS2) out[i] = fminf(fmaxf(CABS * LA[i], 0.0f), 1.0f);
}

static void light_mats(const double ld_in[3], Mat3& R, Mat3& RT) {
    double n = sqrt(ld_in[0]*ld_in[0] + ld_in[1]*ld_in[1] + ld_in[2]*ld_in[2]);
    double l0 = ld_in[0]/n, l1 = ld_in[1]/n, l2 = ld_in[2]/n;
    double yv = -asin(l0);
    if (l2 < 0) yv = -M_PI - yv;
    double yd = yv * 180.0 / M_PI, pd = asin(l1) * 180.0 / M_PI;
    double yr = yd * M_PI / 180.0, pr = pd * M_PI / 180.0;
    float cy = (float)cos(yr), sy = (float)sin(yr), cp = (float)cos(pr), sp = (float)sin(pr);
    float m[9] = { cy,  sy*sp,  sy*cp,
                   0.f, cp,    -sp,
                  -sy,  cy*sp,  cy*cp };
    for (int i = 0; i < 9; ++i) R.m[i] = m[i];
    RT.m[0] = m[0]; RT.m[1] = m[3]; RT.m[2] = m[6];
    RT.m[3] = m[1]; RT.m[4] = m[4]; RT.m[5] = m[7];
    RT.m[6] = m[2]; RT.m[7] = m[5]; RT.m[8] = m[8];
}

// 8-tile half-span (Run granularity)
static F3 half_span8(const Mat3& M) {
    F3 h;
    h.x = 3.5f * (fabsf(M.m[0]) + fabsf(M.m[1]) + fabsf(M.m[2])) + 0.05f;
    h.y = 3.5f * (fabsf(M.m[3]) + fabsf(M.m[4]) + fabsf(M.m[5])) + 0.05f;
    h.z = 3.5f * (fabsf(M.m[6]) + fabsf(M.m[7]) + fabsf(M.m[8])) + 0.05f;
    return h;
}

// 16-deep super-tile half-span; dominates both sub-tiles' H8 boxes
static F3 half_span16(const Mat3& M) {
    F3 h;
    h.x = 3.5f * (fabsf(M.m[0]) + fabsf(M.m[1])) + 7.5f * fabsf(M.m[2]) + 0.1f;
    h.y = 3.5f * (fabsf(M.m[3]) + fabsf(M.m[4])) + 7.5f * fabsf(M.m[5]) + 0.1f;
    h.z = 3.5f * (fabsf(M.m[6]) + fabsf(M.m[7])) + 7.5f * fabsf(M.m[8]) + 0.1f;
    return h;
}

static void h_qc16(const Mat3& M, double ox, double oy, double oz, double q[3]) {
    double cb[3] = { (ox + 3.5) * 2.0 / 223.0 - 1.0,
                     (oy + 3.5) * 2.0 / 223.0 - 1.0,
                     (oz + 7.5) * 2.0 / 223.0 - 1.0 };
    for (int k = 0; k < 3; ++k)
        q[k] = ((double)M.m[3*k] * cb[0] + (double)M.m[3*k+1] * cb[1]
              + (double)M.m[3*k+2] * cb[2]) * 111.5 + 111.5;
}

extern "C" void kernel_launch(void* const* d_in, const int* in_sizes, int n_in,
                              void* d_out, int out_size, void* d_ws, size_t ws_size,
                              hipStream_t stream) {
    const float* d = (const float*)d_in[0];
    float* out = (float*)d_out;

    const double dirs[2][3] = { {2.0, 1.0, 1.0}, {-1.0, 0.5, 0.0} };
    F3 c0 = { 1.0f, 69.0f / 255.0f, 25.0f / 255.0f };
    F3 c1 = { 227.0f / 255.0f, 1.0f, 66.0f / 255.0f };
    Mat3 R[2], RT[2];
    light_mats(dirs[0], R[0], RT[0]);
    light_mats(dirs[1], R[1], RT[1]);
    F3 H8[2]  = { half_span8(R[0]),  half_span8(R[1])  };    // Run/accept8
    F3 H16[2] = { half_span16(R[0]), half_span16(R[1]) };    // k_rot box
    F3 HB[2]  = { half_span16(RT[0]), half_span16(RT[1]) };  // k_back box (16-deep)

    // back-staging boxes provably interior?
    bool bint = true;
    for (int l = 0; l < 2 && bint; ++l) {
        double H[3] = { HB[l].x, HB[l].y, HB[l].z };
        int dim[3] = { BBX, BBY, BBZ };
        for (int tz = 0; tz < NBZ16 && bint; ++tz)
            for (int ty = 0; ty < NT3 && bint; ++ty)
                for (int tx = 0; tx < NT3; ++tx) {
                    double q[3]; h_qc16(RT[l], tx * 8 + PAD, ty * 8 + PAD, tz * 16 + PAD, q);
                    for (int k = 0; k < 3; ++k) {
                        int lo = (int)floor(q[k] - H[k]);
                        if (lo < 1 || lo + dim[k] > LL - 1) { bint = false; break; }
                    }
                    if (!bint) break;
                }
    }

    const size_t f32n = (size_t)(2 * NTZ * LL2 + SS3 + NSEG * SS2 + 2 * SS2);
    const size_t need_A = f32n * 4 + (size_t)2 * LL3 * 2 + 2 * 784 * 2;   // ~66 MB
    const size_t need_C = (size_t)(LL3 + 3 * SS2) * 4;                    // ~45 MB

    if (ws_size >= need_A) {
        float* S0   = (float*)d_ws;
        float* S1   = S0 + NTZ * LL2;
        float* W    = S1 + NTZ * LL2;
        float* Dseg = W + SS3;
        float* A0   = Dseg + NSEG * SS2;
        float* A1   = A0 + SS2;
        __half* T0  = (__half*)(A1 + SS2);
        __half* T1  = T0 + LL3;
        unsigned short* Run = (unsigned short*)(T1 + LL3);

        k_pre  <<<268, 256, 0, stream>>>(d, Dseg, A0, Run, R[0], R[1], H8[0], H8[1]);
        k_rot  <<<ROTG, 512, 0, stream>>>(d, T0, T1, S0, S1, Run,
                                          R[0], R[1], H16[0], H16[1]);
        k_sufw <<<653, 256, 0, stream>>>(S0, S1, Run, d, Dseg, W);
        if (bint)
            k_back<true><<<BACKG, 512, 0, stream>>>(T0, T1, S0, S1, W, A0, A1,
                                                    RT[0], RT[1], HB[0], HB[1]);
        else
            k_back<false><<<BACKG, 512, 0, stream>>>(T0, T1, S0, S1, W, A0, A1,
                                                     RT[0], RT[1], HB[0], HB[1]);
        k_combine<<<(3 * SS2 + 255) / 256, 256, 0, stream>>>(A0, A1, out, c0, c1);
    } else if (ws_size >= need_C) {
        float* T  = (float*)d_ws;
        float* LA = T + LL3;
        for (int l = 0; l < 2; ++l) {
            k_rot_full <<<(LL3 + 255) / 256, 256, 0, stream>>>(d, T, R[l]);
            k_scan_full<<<(LL2 + 255) / 256, 256, 0, stream>>>(T);
            k_fused_back<<<(SS2 + 63) / 64, 64, 0, stream>>>(T, d, LA, RT[l],
                l ? c1.x : c0.x, l ? c1.y : c0.y, l ? c1.z : c0.z, l == 0);
        }
        k_clip<<<(3 * SS2 + 255) / 256, 256, 0, stream>>>(LA, out);
    }
}

// Round 13
// 176.365 us; speedup vs baseline: 1.0247x; 1.0247x over previous
//
#include <hip/hip_runtime.h>
#include <hip/hip_fp16.h>
#include <math.h>

#ifndef M_PI
#define M_PI 3.14159265358979323846
#endif

#define SS   129
#define LL   224
#define LL2  (LL*LL)
#define LL3  (LL*LL*LL)
#define SS2  (SS*SS)
#define SS3  (SS*SS*SS)
#define CABS 0.2f
#define PAD  48

#define BLO 45.5f
#define BHI 178.5f

#define NT1  28                  // 8-tile grid per axis (Run/Ssum granularity)
#define NTZ16 14                 // 16-deep rot super-tiles along z
#define ROTG  (2 * NTZ16 * 784)  // 21952 blocks
#define NT3  17
#define NBZ16 9                  // 16-deep back super-tiles (ceil(129/16))
#define BACKG (2 * NBZ16 * 289)  // 5202 blocks
#define NTZ  28
#define NSEG 4
#define SEGZ 33
#define CVTB 8386                // ceil(SS3/256) d16-conversion blocks

// k_rot staging box: [y:16][z:18][x:21]  (x stride 1, z stride 21, y stride 378)
#define RBX 21
#define RBY 16
#define RBZ 18
#define RBN (RBX*RBY*RBZ)        // 6048 words
#define RSXZ (RBX*RBZ)           // 378 staging threads

// k_back staging box: [y:16][z:19][x:21] (y stride 399, z stride 21)
#define BBX 21
#define BBY 16
#define BBZ 19
#define BBN (BBX*BBY*BBZ)        // 6384 words
#define BSXZ (BBX*BBZ)           // 399 staging threads

struct Mat3 { float m[9]; };
struct F3   { float x, y, z; };

// 8-tile center (Run granularity)
__device__ __forceinline__ F3 tile_center(const Mat3& M, int ox, int oy, int oz) {
    float cbx = fmaf((float)ox + 3.5f, 2.0f / 223.0f, -1.0f);
    float cby = fmaf((float)oy + 3.5f, 2.0f / 223.0f, -1.0f);
    float cbz = fmaf((float)oz + 3.5f, 2.0f / 223.0f, -1.0f);
    F3 qc;
    qc.x = fmaf(fmaf(M.m[0], cbx, fmaf(M.m[1], cby, M.m[2] * cbz)), 111.5f, 111.5f);
    qc.y = fmaf(fmaf(M.m[3], cbx, fmaf(M.m[4], cby, M.m[5] * cbz)), 111.5f, 111.5f);
    qc.z = fmaf(fmaf(M.m[6], cbx, fmaf(M.m[7], cby, M.m[8] * cbz)), 111.5f, 111.5f);
    return qc;
}

// 16-deep super-tile center
__device__ __forceinline__ F3 tile_center16(const Mat3& M, int ox, int oy, int oz) {
    float cbx = fmaf((float)ox + 3.5f, 2.0f / 223.0f, -1.0f);
    float cby = fmaf((float)oy + 3.5f, 2.0f / 223.0f, -1.0f);
    float cbz = fmaf((float)oz + 7.5f, 2.0f / 223.0f, -1.0f);
    F3 qc;
    qc.x = fmaf(fmaf(M.m[0], cbx, fmaf(M.m[1], cby, M.m[2] * cbz)), 111.5f, 111.5f);
    qc.y = fmaf(fmaf(M.m[3], cbx, fmaf(M.m[4], cby, M.m[5] * cbz)), 111.5f, 111.5f);
    qc.z = fmaf(fmaf(M.m[6], cbx, fmaf(M.m[7], cby, M.m[8] * cbz)), 111.5f, 111.5f);
    return qc;
}

__device__ __forceinline__ bool tile_accept(F3 qc, F3 H) {
    return !(qc.x + H.x < BLO || qc.x - H.x > BHI ||
             qc.y + H.y < BLO || qc.y - H.y > BHI ||
             qc.z + H.z < BLO || qc.z - H.z > BHI);
}

__device__ __forceinline__ void qmap(const Mat3& M, int x, int y, int z,
                                     float& qx, float& qy, float& qz) {
    float bx = fmaf((float)x, 2.0f / 223.0f, -1.0f);
    float by = fmaf((float)y, 2.0f / 223.0f, -1.0f);
    float bz = fmaf((float)z, 2.0f / 223.0f, -1.0f);
    qx = fmaf(fmaf(M.m[0], bx, fmaf(M.m[1], by, M.m[2] * bz)), 111.5f, 111.5f);
    qy = fmaf(fmaf(M.m[3], bx, fmaf(M.m[4], by, M.m[5] * bz)), 111.5f, 111.5f);
    qz = fmaf(fmaf(M.m[6], bx, fmaf(M.m[7], by, M.m[8] * bz)), 111.5f, 111.5f);
}

__device__ __forceinline__ float fetch_d(const float* __restrict__ d, int z, int y, int x) {
    unsigned zz = (unsigned)(z - PAD), yy = (unsigned)(y - PAD), xx = (unsigned)(x - PAD);
    return (zz < (unsigned)SS && yy < (unsigned)SS && xx < (unsigned)SS)
        ? d[((int)zz * SS + (int)yy) * SS + (int)xx] : 0.0f;
}

__device__ __forceinline__ float fetch_d16(const __half* __restrict__ d, int z, int y, int x) {
    unsigned zz = (unsigned)(z - PAD), yy = (unsigned)(y - PAD), xx = (unsigned)(x - PAD);
    return (zz < (unsigned)SS && yy < (unsigned)SS && xx < (unsigned)SS)
        ? __half2float(d[((int)zz * SS + (int)yy) * SS + (int)xx]) : 0.0f;
}

__device__ __forceinline__ float fetch_T(const float* __restrict__ T, int z, int y, int x) {
    unsigned zz = (unsigned)z, yy = (unsigned)y, xx = (unsigned)x;
    return (zz < (unsigned)LL && yy < (unsigned)LL && xx < (unsigned)LL)
        ? T[((int)zz * LL + (int)yy) * LL + (int)xx] : 0.0f;
}

__device__ __forceinline__ float tri_T(const float* __restrict__ T, float qz, float qy, float qx) {
    int x0 = (int)floorf(qx), y0 = (int)floorf(qy), z0 = (int)floorf(qz);
    float wx = qx - (float)x0, wy = qy - (float)y0, wz = qz - (float)z0;
    float c000 = fetch_T(T, z0, y0, x0),     c001 = fetch_T(T, z0, y0, x0 + 1);
    float c010 = fetch_T(T, z0, y0 + 1, x0), c011 = fetch_T(T, z0, y0 + 1, x0 + 1);
    float c100 = fetch_T(T, z0 + 1, y0, x0),     c101 = fetch_T(T, z0 + 1, y0, x0 + 1);
    float c110 = fetch_T(T, z0 + 1, y0 + 1, x0), c111 = fetch_T(T, z0 + 1, y0 + 1, x0 + 1);
    float a00 = c000 + wx * (c001 - c000), a01 = c010 + wx * (c011 - c010);
    float a10 = c100 + wx * (c101 - c100), a11 = c110 + wx * (c111 - c110);
    float b0 = a00 + wy * (a01 - a00), b1 = a10 + wy * (a11 - a10);
    return b0 + wz * (b1 - b0);
}

__device__ __forceinline__ float tri_d_g(const float* __restrict__ d, float qz, float qy, float qx) {
    int x0 = (int)floorf(qx), y0 = (int)floorf(qy), z0 = (int)floorf(qz);
    float wx = qx - (float)x0, wy = qy - (float)y0, wz = qz - (float)z0;
    float c000 = fetch_d(d, z0, y0, x0),     c001 = fetch_d(d, z0, y0, x0 + 1);
    float c010 = fetch_d(d, z0, y0 + 1, x0), c011 = fetch_d(d, z0, y0 + 1, x0 + 1);
    float c100 = fetch_d(d, z0 + 1, y0, x0),     c101 = fetch_d(d, z0 + 1, y0, x0 + 1);
    float c110 = fetch_d(d, z0 + 1, y0 + 1, x0), c111 = fetch_d(d, z0 + 1, y0 + 1, x0 + 1);
    float a00 = c000 + wx * (c001 - c000), a01 = c010 + wx * (c011 - c010);
    float a10 = c100 + wx * (c101 - c100), a11 = c110 + wx * (c111 - c110);
    float b0 = a00 + wy * (a01 - a00), b1 = a10 + wy * (a11 - a10);
    return b0 + wz * (b1 - b0);
}

// trilinear from k_rot's [y:16][z:18][x:21] box
__device__ __forceinline__ float tri_rot(const float* __restrict__ S,
                                         float qx, float qy, float qz,
                                         int lox, int loy, int loz) {
    int x0 = (int)floorf(qx), y0 = (int)floorf(qy), z0 = (int)floorf(qz);
    float wx = qx - (float)x0, wy = qy - (float)y0, wz = qz - (float)z0;
    int i = (y0 - loy) * 378 + (z0 - loz) * 21 + (x0 - lox);
    float c000 = S[i],        c001 = S[i + 1];
    float cz0  = S[i + 21],   cz1  = S[i + 22];
    float cy0  = S[i + 378],  cy1  = S[i + 379];
    float cw0  = S[i + 399],  cw1  = S[i + 400];
    float a00 = c000 + wx * (c001 - c000);
    float a01 = cy0  + wx * (cy1  - cy0);
    float a10 = cz0  + wx * (cz1  - cz0);
    float a11 = cw0  + wx * (cw1  - cw0);
    float b0  = a00 + wy * (a01 - a00);
    float b1  = a10 + wy * (a11 - a10);
    return b0 + wz * (b1 - b0);
}

// trilinear from k_back's [y:16][z:19][x:21] box
__device__ __forceinline__ float tri_back(const float* __restrict__ S,
                                          float qx, float qy, float qz,
                                          int lox, int loy, int loz) {
    int x0 = (int)floorf(qx), y0 = (int)floorf(qy), z0 = (int)floorf(qz);
    float wx = qx - (float)x0, wy = qy - (float)y0, wz = qz - (float)z0;
    int i = (y0 - loy) * 399 + (z0 - loz) * 21 + (x0 - lox);
    float c000 = S[i],        c001 = S[i + 1];
    float cz0  = S[i + 21],   cz1  = S[i + 22];
    float cy0  = S[i + 399],  cy1  = S[i + 400];
    float cw0  = S[i + 420],  cw1  = S[i + 421];
    float a00 = c000 + wx * (c001 - c000);
    float a01 = cy0  + wx * (cy1  - cy0);
    float a10 = cz0  + wx * (cz1  - cz0);
    float a11 = cw0  + wx * (cw1  - cw0);
    float b0  = a00 + wy * (a01 - a00);
    float b1  = a10 + wy * (a11 - a10);
    return b0 + wz * (b1 - b0);
}

// k_pre: blocks [0,261): view-ray segment sums + zero accumulators;
//        blocks [261,268): Run table build;
//        blocks [268,268+CVTB): d -> fp16 conversion
__global__ __launch_bounds__(256) void k_pre(const float* __restrict__ d,
        float* __restrict__ Dseg, float* __restrict__ A,
        unsigned short* __restrict__ Run, __half* __restrict__ d16,
        Mat3 M0, Mat3 M1, F3 H0, F3 H1) {
    int b = blockIdx.x;
    if (b < 261) {
        int t = b * 256 + threadIdx.x;
        if (t < 2 * SS2) A[t] = 0.0f;
        if (t >= NSEG * SS2) return;
        int seg = t / SS2, col = t - seg * SS2;
        int zs = seg * SEGZ, ze = min(SS, zs + SEGZ);
        float run = 0.0f;
        for (int z = zs; z < ze; ++z) run += d[z * SS2 + col];
        Dseg[t] = run;
    } else if (b < 268) {
        int id = (b - 261) * 256 + threadIdx.x;
        if (id >= 2 * 784) return;
        int l = id / 784, r = id - l * 784;
        int ty = r / 28, tx = r - ty * 28;
        const Mat3 M = l ? M1 : M0;
        const F3  H  = l ? H1 : H0;
        int t0 = -1, t1 = -1;
        for (int tz = 0; tz < NT1; ++tz) {
            F3 qc = tile_center(M, tx * 8, ty * 8, tz * 8);
            if (tile_accept(qc, H)) { if (t0 < 0) t0 = tz; t1 = tz; }
        }
        Run[id] = (t0 < 0) ? 0xFFFFu : (unsigned short)(t0 | (t1 << 8));
    } else {
        int t = (b - 268) * 256 + threadIdx.x;
        if (t < SS3) d16[t] = __float2half(d[t]);
    }
}

// K1: 8x8x16 super-tile per block; stages from d16 (fp16), all arithmetic f32
__global__ __launch_bounds__(512) void k_rot(const __half* __restrict__ d16,
        __half* __restrict__ T0, __half* __restrict__ T1,
        float* __restrict__ S0, float* __restrict__ S1,
        const unsigned short* __restrict__ Run,
        Mat3 M0, Mat3 M1, F3 H0, F3 H1) {
    int b = blockIdx.x;
    int light = b / (NTZ16 * 784);
    int r = b - light * (NTZ16 * 784);
    int tz16 = r / 784;
    int r2 = r - tz16 * 784;
    int tty = r2 / 28, ttx = r2 - tty * 28;

    unsigned short rt = Run[light * 784 + tty * 28 + ttx];
    if (rt == 0xFFFFu) return;
    int t0 = rt & 0xFF, t1 = rt >> 8;
    if (2 * tz16 + 1 < t0 || 2 * tz16 > t1) return;

    const Mat3 M = light ? M1 : M0;
    const F3  H  = light ? H1 : H0;           // H16
    __half* __restrict__ T   = light ? T1 : T0;
    float* __restrict__ Ssum = light ? S1 : S0;

    int ox = ttx * 8, oy = tty * 8, oz = tz16 * 16;
    F3 qc = tile_center16(M, ox, oy, oz);

    int lox = (int)floorf(qc.x - H.x);
    int loy = (int)floorf(qc.y - H.y);
    int loz = (int)floorf(qc.z - H.z);

    __shared__ float S[RBN];
    __shared__ float Sc[1024];
    int tid = threadIdx.x;

    if (tid < RSXZ) {
        int ix = tid % RBX, iz = tid / RBX;
        bool interior = (lox >= PAD) & (lox <= PAD + SS - RBX) &
                        (loy >= PAD) & (loy <= PAD + SS - RBY) &
                        (loz >= PAD) & (loz <= PAD + SS - RBZ);
        if (interior) {
            const __half* g = d16 + ((size_t)(loz + iz - PAD) * SS + (loy - PAD)) * SS
                                  + (lox + ix - PAD);
            #pragma unroll
            for (int j = 0; j < RBY; ++j)
                S[tid + j * RSXZ] = __half2float(g[j * SS]);
        } else {
            #pragma unroll
            for (int j = 0; j < RBY; ++j)
                S[tid + j * RSXZ] = fetch_d16(d16, loz + iz, loy + j, lox + ix);
        }
    }
    __syncthreads();

    int lx = tid & 7, ly = (tid >> 3) & 7, lz = tid >> 6;
    int col = tid & 63;
    float fx = (float)lx - 3.5f, fy = (float)ly - 3.5f, fz = (float)lz - 7.5f;
    float qx = qc.x + fmaf(M.m[0], fx, fmaf(M.m[1], fy, M.m[2] * fz));
    float qy = qc.y + fmaf(M.m[3], fx, fmaf(M.m[4], fy, M.m[5] * fz));
    float qz = qc.z + fmaf(M.m[6], fx, fmaf(M.m[7], fy, M.m[8] * fz));
    float v0 = tri_rot(S, qx, qy, qz, lox, loy, loz);
    float qx2 = qx + 8.0f * M.m[2];
    float qy2 = qy + 8.0f * M.m[5];
    float qz2 = qz + 8.0f * M.m[8];
    float v1 = tri_rot(S, qx2, qy2, qz2, lox, loy, loz);

    Sc[lz * 64 + col] = v0;
    Sc[(lz + 8) * 64 + col] = v1;
    __syncthreads();
    if (tid < 64) {
        int so = (oy + (tid >> 3)) * LL + (ox + (tid & 7));
        float s = 0.0f;
        #pragma unroll
        for (int k = 15; k >= 8; --k) { s += Sc[k * 64 + tid]; Sc[k * 64 + tid] = s; }
        Ssum[(2 * tz16 + 1) * LL2 + so] = s;
        float s2 = 0.0f;
        #pragma unroll
        for (int k = 7; k >= 0; --k) { s2 += Sc[k * 64 + tid]; Sc[k * 64 + tid] = s2; }
        Ssum[(2 * tz16) * LL2 + so] = s2;
    }
    __syncthreads();
    int to = (oy + ly) * LL + (ox + lx);
    T[(size_t)(oz + lz) * LL2 + to]     = __float2half(Sc[lz * 64 + col]);
    T[(size_t)(oz + 8 + lz) * LL2 + to] = __float2half(Sc[(lz + 8) * 64 + col]);
}

// k_sufw: blocks [0,392): per-column exclusive suffix-above of tile totals;
//         blocks [392,653): W write (fp16)
__global__ __launch_bounds__(256) void k_sufw(float* __restrict__ S0,
        float* __restrict__ S1, const unsigned short* __restrict__ Run,
        const float* __restrict__ d, const float* __restrict__ Dseg,
        __half* __restrict__ W) {
    int b = blockIdx.x;
    if (b < 392) {
        int l = b / 196;
        int col = (b - l * 196) * 256 + threadIdx.x;   // < LL2 exactly
        float* __restrict__ Ssum = l ? S1 : S0;
        int x = col % LL, y = col / LL;
        unsigned short r = Run[l * 784 + (y >> 3) * 28 + (x >> 3)];
        if (r == 0xFFFFu) return;
        int t0 = r & 0xFF, t1 = r >> 8;
        float vbuf[NTZ];
        #pragma unroll
        for (int t = 0; t < NTZ; ++t)
            vbuf[t] = (t >= t0 && t <= t1) ? Ssum[t * LL2 + col] : 0.0f;
        float run = 0.0f;
        #pragma unroll
        for (int t = NTZ - 1; t >= 0; --t) {
            if (t >= t0 && t <= t1) Ssum[t * LL2 + col] = run;
            run += vbuf[t];
        }
    } else {
        int t = (b - 392) * 256 + threadIdx.x;
        if (t >= NSEG * SS2) return;
        int seg = t / SS2, col = t - seg * SS2;
        int zs = seg * SEGZ, ze = min(SS, zs + SEGZ);
        float run = 0.0f;
        for (int s2 = seg + 1; s2 < NSEG; ++s2) run += Dseg[s2 * SS2 + col];
        for (int z = ze - 1; z >= zs; --z) {
            float dv = d[z * SS2 + col];
            run += dv;
            W[z * SS2 + col] = __float2half(dv * __expf(-CABS * run));
        }
    }
}

// K3: 8x8x16 super-tile; stage exp(-c*(T16+seed)), back-rotate, *W16, reduce
template<bool BINT>
__global__ __launch_bounds__(512) void k_back(const __half* __restrict__ T0,
        const __half* __restrict__ T1, const float* __restrict__ S0,
        const float* __restrict__ S1, const __half* __restrict__ W,
        float* __restrict__ A0, float* __restrict__ A1,
        Mat3 M0, Mat3 M1, F3 H0, F3 H1) {
    int b = blockIdx.x;
    int light = b / (NBZ16 * 289); b -= light * (NBZ16 * 289);
    int tz16 = b / 289;
    int r2 = b - tz16 * 289;
    int tty = r2 / 17, ttx = r2 - tty * 17;

    const Mat3 M = light ? M1 : M0;
    const F3  H  = light ? H1 : H0;           // H16 (back)
    const __half* __restrict__ T   = light ? T1 : T0;
    const float* __restrict__ Ssum = light ? S1 : S0;
    float* __restrict__ A = light ? A1 : A0;

    int ox = ttx * 8, oy = tty * 8, oz = tz16 * 16;
    F3 qc = tile_center16(M, ox + PAD, oy + PAD, oz + PAD);
    int lox = (int)floorf(qc.x - H.x);
    int loy = (int)floorf(qc.y - H.y);
    int loz = (int)floorf(qc.z - H.z);

    __shared__ float S[BBN];
    __shared__ float Sc[1024];
    int tid = threadIdx.x;

    if (tid < BSXZ) {
        int ix = tid % BBX, iz = tid / BBX;
        if (BINT) {
            const __half* tb = T + ((size_t)(loz + iz) * LL + loy) * LL + (lox + ix);
            const float* sb = Ssum + (size_t)((loz + iz) >> 3) * LL2 + loy * LL + (lox + ix);
            #pragma unroll
            for (int j = 0; j < BBY; ++j)
                S[tid + j * BSXZ] = __expf(-CABS * (__half2float(tb[j * LL]) + sb[j * LL]));
        } else {
            #pragma unroll
            for (int j = 0; j < BBY; ++j) {
                int gz = loz + iz, gy = loy + j, gx = lox + ix;
                bool inb = ((unsigned)gz < (unsigned)LL) & ((unsigned)gy < (unsigned)LL)
                         & ((unsigned)gx < (unsigned)LL);
                float e = 0.0f;
                if (inb)
                    e = __expf(-CABS * (__half2float(T[((size_t)gz * LL + gy) * LL + gx])
                                      + Ssum[(size_t)(gz >> 3) * LL2 + gy * LL + gx]));
                S[tid + j * BSXZ] = e;
            }
        }
    }
    __syncthreads();

    int lx = tid & 7, ly = (tid >> 3) & 7, lz = tid >> 6;
    int col = tid & 63;
    int x = ox + lx, y = oy + ly;
    float v0 = 0.0f, v1 = 0.0f;
    if (x < SS && y < SS) {
        float fx = (float)lx - 3.5f, fy = (float)ly - 3.5f, fz = (float)lz - 7.5f;
        float qx = qc.x + fmaf(M.m[0], fx, fmaf(M.m[1], fy, M.m[2] * fz));
        float qy = qc.y + fmaf(M.m[3], fx, fmaf(M.m[4], fy, M.m[5] * fz));
        float qz = qc.z + fmaf(M.m[6], fx, fmaf(M.m[7], fy, M.m[8] * fz));
        int z0 = oz + lz, z1 = oz + 8 + lz;
        if (z0 < SS)
            v0 = tri_back(S, qx, qy, qz, lox, loy, loz)
               * __half2float(W[(z0 * SS + y) * SS + x]);
        if (z1 < SS) {
            float qx2 = qx + 8.0f * M.m[2];
            float qy2 = qy + 8.0f * M.m[5];
            float qz2 = qz + 8.0f * M.m[8];
            v1 = tri_back(S, qx2, qy2, qz2, lox, loy, loz)
               * __half2float(W[(z1 * SS + y) * SS + x]);
        }
    }
    Sc[lz * 64 + col] = v0;
    Sc[(lz + 8) * 64 + col] = v1;
    __syncthreads();
    if (tid < 64) {
        float s = 0.0f;
        #pragma unroll
        for (int k = 0; k < 16; ++k) s += Sc[k * 64 + tid];
        int xx = ox + (tid & 7), yy = oy + (tid >> 3);
        if (xx < SS && yy < SS) atomicAdd(&A[yy * SS + xx], s);
    }
}

__global__ __launch_bounds__(256) void k_combine(const float* __restrict__ A0,
        const float* __restrict__ A1, float* __restrict__ out, F3 c0, F3 c1) {
    int i = blockIdx.x * 256 + threadIdx.x;
    if (i >= 3 * SS2) return;
    int ch = i / SS2, col = i - ch * SS2;
    float r0 = (ch == 0) ? c0.x : ((ch == 1) ? c0.y : c0.z);
    float r1 = (ch == 0) ? c1.x : ((ch == 1) ? c1.y : c1.z);
    float o = CABS * (A0[col] * r0 + A1[col] * r1);
    out[i] = fminf(fmaxf(o, 0.0f), 1.0f);
}

// ---- minimal-workspace fallback ----
__global__ __launch_bounds__(256) void k_rot_full(const float* __restrict__ d,
                                                  float* __restrict__ T, Mat3 R) {
    int i = blockIdx.x * 256 + threadIdx.x;
    if (i >= LL3) return;
    int x = i % LL; int r = i / LL; int y = r % LL; int z = r / LL;
    float qx, qy, qz; qmap(R, x, y, z, qx, qy, qz);
    T[i] = tri_d_g(d, qz, qy, qx);
}

__global__ __launch_bounds__(256) void k_scan_full(float* __restrict__ T) {
    int col = blockIdx.x * 256 + threadIdx.x;
    if (col >= LL2) return;
    float run = 0.0f;
    for (int z = LL - 1; z >= 0; --z) {
        int idx = z * LL2 + col;
        run += T[idx];
        T[idx] = __expf(-CABS * run);
    }
}

__global__ __launch_bounds__(64) void k_fused_back(const float* __restrict__ T,
        const float* __restrict__ d, float* __restrict__ LA, Mat3 RT,
        float cr, float cg, float cb, int first) {
    int col = blockIdx.x * 64 + threadIdx.x;
    if (col >= SS2) return;
    int y = col / SS, x = col % SS;
    float run = 0.0f, acc = 0.0f;
    for (int z = SS - 1; z >= 0; --z) {
        float qx, qy, qz; qmap(RT, x + PAD, y + PAD, z + PAD, qx, qy, qz);
        float u = tri_T(T, qz, qy, qx);
        float dv = d[z * SS2 + col];
        run += dv;
        acc = fmaf(dv * __expf(-CABS * run), u, acc);
    }
    if (first) {
        LA[0 * SS2 + col] = acc * cr;
        LA[1 * SS2 + col] = acc * cg;
        LA[2 * SS2 + col] = acc * cb;
    } else {
        LA[0 * SS2 + col] += acc * cr;
        LA[1 * SS2 + col] += acc * cg;
        LA[2 * SS2 + col] += acc * cb;
    }
}

__global__ __launch_bounds__(256) void k_clip(const float* __restrict__ LA,
                                              float* __restrict__ out) {
    int i = blockIdx.x * 256 + threadIdx.x;
    if (i < 3 * SS2) out[i] = fminf(fmaxf(CABS * LA[i], 0.0f), 1.0f);
}

static void light_mats(const double ld_in[3], Mat3& R, Mat3& RT) {
    double n = sqrt(ld_in[0]*ld_in[0] + ld_in[1]*ld_in[1] + ld_in[2]*ld_in[2]);
    double l0 = ld_in[0]/n, l1 = ld_in[1]/n, l2 = ld_in[2]/n;
    double yv = -asin(l0);
    if (l2 < 0) yv = -M_PI - yv;
    double yd = yv * 180.0 / M_PI, pd = asin(l1) * 180.0 / M_PI;
    double yr = yd * M_PI / 180.0, pr = pd * M_PI / 180.0;
    float cy = (float)cos(yr), sy = (float)sin(yr), cp = (float)cos(pr), sp = (float)sin(pr);
    float m[9] = { cy,  sy*sp,  sy*cp,
                   0.f, cp,    -sp,
                  -sy,  cy*sp,  cy*cp };
    for (int i = 0; i < 9; ++i) R.m[i] = m[i];
    RT.m[0] = m[0]; RT.m[1] = m[3]; RT.m[2] = m[6];
    RT.m[3] = m[1]; RT.m[4] = m[4]; RT.m[5] = m[7];
    RT.m[6] = m[2]; RT.m[7] = m[5]; RT.m[8] = m[8];
}

// 8-tile half-span (Run granularity)
static F3 half_span8(const Mat3& M) {
    F3 h;
    h.x = 3.5f * (fabsf(M.m[0]) + fabsf(M.m[1]) + fabsf(M.m[2])) + 0.05f;
    h.y = 3.5f * (fabsf(M.m[3]) + fabsf(M.m[4]) + fabsf(M.m[5])) + 0.05f;
    h.z = 3.5f * (fabsf(M.m[6]) + fabsf(M.m[7]) + fabsf(M.m[8])) + 0.05f;
    return h;
}

// 16-deep super-tile half-span; dominates both sub-tiles' H8 boxes
static F3 half_span16(const Mat3& M) {
    F3 h;
    h.x = 3.5f * (fabsf(M.m[0]) + fabsf(M.m[1])) + 7.5f * fabsf(M.m[2]) + 0.1f;
    h.y = 3.5f * (fabsf(M.m[3]) + fabsf(M.m[4])) + 7.5f * fabsf(M.m[5]) + 0.1f;
    h.z = 3.5f * (fabsf(M.m[6]) + fabsf(M.m[7])) + 7.5f * fabsf(M.m[8]) + 0.1f;
    return h;
}

static void h_qc16(const Mat3& M, double ox, double oy, double oz, double q[3]) {
    double cb[3] = { (ox + 3.5) * 2.0 / 223.0 - 1.0,
                     (oy + 3.5) * 2.0 / 223.0 - 1.0,
                     (oz + 7.5) * 2.0 / 223.0 - 1.0 };
    for (int k = 0; k < 3; ++k)
        q[k] = ((double)M.m[3*k] * cb[0] + (double)M.m[3*k+1] * cb[1]
              + (double)M.m[3*k+2] * cb[2]) * 111.5 + 111.5;
}

extern "C" void kernel_launch(void* const* d_in, const int* in_sizes, int n_in,
                              void* d_out, int out_size, void* d_ws, size_t ws_size,
                              hipStream_t stream) {
    const float* d = (const float*)d_in[0];
    float* out = (float*)d_out;

    const double dirs[2][3] = { {2.0, 1.0, 1.0}, {-1.0, 0.5, 0.0} };
    F3 c0 = { 1.0f, 69.0f / 255.0f, 25.0f / 255.0f };
    F3 c1 = { 227.0f / 255.0f, 1.0f, 66.0f / 255.0f };
    Mat3 R[2], RT[2];
    light_mats(dirs[0], R[0], RT[0]);
    light_mats(dirs[1], R[1], RT[1]);
    F3 H8[2]  = { half_span8(R[0]),  half_span8(R[1])  };    // Run/accept8
    F3 H16[2] = { half_span16(R[0]), half_span16(R[1]) };    // k_rot box
    F3 HB[2]  = { half_span16(RT[0]), half_span16(RT[1]) };  // k_back box (16-deep)

    // back-staging boxes provably interior?
    bool bint = true;
    for (int l = 0; l < 2 && bint; ++l) {
        double H[3] = { HB[l].x, HB[l].y, HB[l].z };
        int dim[3] = { BBX, BBY, BBZ };
        for (int tz = 0; tz < NBZ16 && bint; ++tz)
            for (int ty = 0; ty < NT3 && bint; ++ty)
                for (int tx = 0; tx < NT3; ++tx) {
                    double q[3]; h_qc16(RT[l], tx * 8 + PAD, ty * 8 + PAD, tz * 16 + PAD, q);
                    for (int k = 0; k < 3; ++k) {
                        int lo = (int)floor(q[k] - H[k]);
                        if (lo < 1 || lo + dim[k] > LL - 1) { bint = false; break; }
                    }
                    if (!bint) break;
                }
    }

    // layout: f32 blocks, then halves (W, d16, T0, T1), then Run
    const size_t f32n = (size_t)(2 * NTZ * LL2 + NSEG * SS2 + 2 * SS2);
    const size_t need_A = f32n * 4 + (size_t)(2 * SS3 + 2 * LL3) * 2 + 2 * 784 * 2; // ~65 MB
    const size_t need_C = (size_t)(LL3 + 3 * SS2) * 4;                              // ~45 MB

    if (ws_size >= need_A) {
        float* S0   = (float*)d_ws;
        float* S1   = S0 + NTZ * LL2;
        float* Dseg = S1 + NTZ * LL2;
        float* A0   = Dseg + NSEG * SS2;
        float* A1   = A0 + SS2;
        __half* W   = (__half*)(A1 + SS2);
        __half* d16 = W + SS3;
        __half* T0  = d16 + SS3;
        __half* T1  = T0 + LL3;
        unsigned short* Run = (unsigned short*)(T1 + LL3);

        k_pre  <<<268 + CVTB, 256, 0, stream>>>(d, Dseg, A0, Run, d16,
                                                R[0], R[1], H8[0], H8[1]);
        k_rot  <<<ROTG, 512, 0, stream>>>(d16, T0, T1, S0, S1, Run,
                                          R[0], R[1], H16[0], H16[1]);
        k_sufw <<<653, 256, 0, stream>>>(S0, S1, Run, d, Dseg, W);
        if (bint)
            k_back<true><<<BACKG, 512, 0, stream>>>(T0, T1, S0, S1, W, A0, A1,
                                                    RT[0], RT[1], HB[0], HB[1]);
        else
            k_back<false><<<BACKG, 512, 0, stream>>>(T0, T1, S0, S1, W, A0, A1,
                                                     RT[0], RT[1], HB[0], HB[1]);
        k_combine<<<(3 * SS2 + 255) / 256, 256, 0, stream>>>(A0, A1, out, c0, c1);
    } else if (ws_size >= need_C) {
        float* T  = (float*)d_ws;
        float* LA = T + LL3;
        for (int l = 0; l < 2; ++l) {
            k_rot_full <<<(LL3 + 255) / 256, 256, 0, stream>>>(d, T, R[l]);
            k_scan_full<<<(LL2 + 255) / 256, 256, 0, stream>>>(T);
            k_fused_back<<<(SS2 + 63) / 64, 64, 0, stream>>>(T, d, LA, RT[l],
                l ? c1.x : c0.x, l ? c1.y : c0.y, l ? c1.z : c0.z, l == 0);
        }
        k_clip<<<(3 * SS2 + 255) / 256, 256, 0, stream>>>(LA, out);
    }
}